// Round 1
// baseline (33.959 us; speedup 1.0000x reference)
//
#include <hip/hip_runtime.h>
#include <math.h>

#define NROWS 9
#define DIN   128
#define DH    128
#define DOUT  384
#define NTHR  512
#define NWAVE (NTHR / 64)

__global__ __launch_bounds__(NTHR) void msg_kernel(
    const float* __restrict__ input1, const float* __restrict__ input2,
    const float* __restrict__ v_j,    const float* __restrict__ s_j,
    const float* __restrict__ v_norm,
    const float* __restrict__ W1,     const float* __restrict__ b1,
    const float* __restrict__ W2,     const float* __restrict__ b2,
    const float* __restrict__ Wr,     const float* __restrict__ br,
    float* __restrict__ out)
{
    __shared__ float sA[NROWS * DIN];     // input1 rows 0..8
    __shared__ float sH[NROWS * DH];      // hidden after silu
    __shared__ float sOut[NROWS * DOUT];  // out rows 0..8
    __shared__ float wc1[NWAVE], wtot[NWAVE];

    const int tid = threadIdx.x;

    // stage input1 rows 0..8
    for (int i = tid; i < NROWS * DIN; i += NTHR)
        sA[i] = input1[i];
    __syncthreads();

    // h = silu(A @ W1 + b1); task t = (row i, col k)
    for (int t = tid; t < NROWS * DH; t += NTHR) {
        const int i = t / DH, k = t % DH;
        float acc = b1[k];
        const float* a = &sA[i * DIN];
        #pragma unroll 8
        for (int d = 0; d < DIN; ++d)
            acc = fmaf(a[d], W1[d * DH + k], acc);
        // silu
        sH[t] = acc / (1.0f + __expf(-acc));
    }
    __syncthreads();

    const float f_c = 0.5f * cosf(3.14159265358979323846f * 1.5f / 5.0f) + 1.0f;

    // out = (H @ W2 + b2) * ((input2 @ Wr + br) * f_c); task t = (row i, col j)
    for (int t = tid; t < NROWS * DOUT; t += NTHR) {
        const int i = t / DOUT, j = t % DOUT;
        float acc = b2[j];
        const float* h = &sH[i * DH];
        #pragma unroll 8
        for (int k = 0; k < DH; ++k)
            acc = fmaf(h[k], W2[k * DOUT + j], acc);
        const float w = (input2[i] * Wr[j] + br[j]) * f_c;
        sOut[t] = acc * w;
    }
    __syncthreads();

    // reductions over 3*384 flattened (rows are contiguous in sOut):
    //   sumc1 = sum(out[3:6]);  tot = sum(out[0:3]*v_j + out[6:9]*v_norm)
    float pc1 = 0.0f, ptot = 0.0f;
    for (int t = tid; t < 3 * DOUT; t += NTHR) {
        pc1  += sOut[3 * DOUT + t];
        ptot += sOut[t] * v_j[t] + sOut[6 * DOUT + t] * v_norm[t];
    }
    // wave64 tree reduce
    for (int off = 32; off > 0; off >>= 1) {
        pc1  += __shfl_down(pc1,  off);
        ptot += __shfl_down(ptot, off);
    }
    const int wave = tid >> 6, lane = tid & 63;
    if (lane == 0) { wc1[wave] = pc1; wtot[wave] = ptot; }
    __syncthreads();

    float sumc1 = 0.0f, total = 0.0f;
    #pragma unroll
    for (int w = 0; w < NWAVE; ++w) { sumc1 += wc1[w]; total += wtot[w]; }

    // v_m = total + v_j  (broadcast scalar), s_m = sumc1 + s_j
    for (int t = tid; t < 3 * DOUT; t += NTHR)
        out[t] = total + v_j[t];
    if (tid == 0)
        out[3 * DOUT] = sumc1 + s_j[0];
}

extern "C" void kernel_launch(void* const* d_in, const int* in_sizes, int n_in,
                              void* d_out, int out_size, void* d_ws, size_t ws_size,
                              hipStream_t stream) {
    const float* input1 = (const float*)d_in[0];
    const float* input2 = (const float*)d_in[1];
    const float* v_j    = (const float*)d_in[2];
    const float* s_j    = (const float*)d_in[3];
    const float* v_norm = (const float*)d_in[4];
    const float* W1     = (const float*)d_in[5];
    const float* b1     = (const float*)d_in[6];
    const float* W2     = (const float*)d_in[7];
    const float* b2     = (const float*)d_in[8];
    const float* Wr     = (const float*)d_in[9];
    const float* br     = (const float*)d_in[10];
    float* out = (float*)d_out;

    msg_kernel<<<1, NTHR, 0, stream>>>(input1, input2, v_j, s_j, v_norm,
                                       W1, b1, W2, b2, Wr, br, out);
}

// Round 2
// 22.709 us; speedup vs baseline: 1.4954x; 1.4954x over previous
//
#include <hip/hip_runtime.h>
#include <math.h>

#define NROWS 9
#define DIN   128
#define DH    128
#define DOUT  384
#define NTHR  512

__device__ __forceinline__ float readlane_f(float v, int l) {
    return __int_as_float(__builtin_amdgcn_readlane(__float_as_int(v), l));
}

__global__ __launch_bounds__(NTHR) void msg_kernel(
    const float* __restrict__ input1, const float* __restrict__ input2,
    const float* __restrict__ v_j,    const float* __restrict__ s_j,
    const float* __restrict__ v_norm,
    const float* __restrict__ W1,     const float* __restrict__ b1,
    const float* __restrict__ W2,     const float* __restrict__ b2,
    const float* __restrict__ Wr,     const float* __restrict__ br,
    float* __restrict__ out)
{
    __shared__ float sPart[4][NROWS][DH];   // layer-1 partials (18 KB)
    __shared__ float sH[NROWS * DH];        // hidden after silu (4.5 KB)
    __shared__ float red[2][8];             // wave reduction slots

    const int t    = threadIdx.x;
    const int lane = t & 63;
    const int wave = t >> 6;

    // ---- stage input1 rows 0..8 into registers (replicated per wave) ----
    // areg[r] holds input1[r*64 + lane]; flat p = i*128 + d -> r = 2i + (d>>6), l = d&63
    float areg[18];
    #pragma unroll
    for (int r = 0; r < 18; ++r)
        areg[r] = input1[r * 64 + lane];

    // ---- Phase A: h = silu(A @ W1 + b1), d-dim split 4 ways across waves ----
    const int kc = t & 127;                              // output column 0..127
    const int q  = __builtin_amdgcn_readfirstlane(t >> 7); // d-quarter, wave-uniform SGPR
    float acc[NROWS];
    #pragma unroll
    for (int i = 0; i < NROWS; ++i) acc[i] = 0.0f;

    if (q < 2) {                    // d in [0,64): areg index 2i, lane = d
        const int d0 = q * 32;
        #pragma unroll 8
        for (int dd = 0; dd < 32; ++dd) {
            const int d = d0 + dd;
            const float w1v = W1[d * DH + kc];
            #pragma unroll
            for (int i = 0; i < NROWS; ++i)
                acc[i] = fmaf(readlane_f(areg[2 * i], d), w1v, acc[i]);
        }
    } else {                        // d in [64,128): areg index 2i+1, lane = d-64
        const int d0 = q * 32;
        #pragma unroll 8
        for (int dd = 0; dd < 32; ++dd) {
            const int d = d0 + dd;
            const float w1v = W1[d * DH + kc];
            #pragma unroll
            for (int i = 0; i < NROWS; ++i)
                acc[i] = fmaf(readlane_f(areg[2 * i + 1], d - 64), w1v, acc[i]);
        }
    }
    #pragma unroll
    for (int i = 0; i < NROWS; ++i)
        sPart[q][i][kc] = acc[i];
    __syncthreads();

    if (t < DH) {
        #pragma unroll
        for (int i = 0; i < NROWS; ++i) {
            float h = sPart[0][i][t] + sPart[1][i][t] + sPart[2][i][t] + sPart[3][i][t] + b1[t];
            sH[i * DH + t] = h / (1.0f + __expf(-h));
        }
    }
    __syncthreads();

    // ---- redistribute h into registers: hreg[r] = sH[r*64 + lane] ----
    float hreg[18];
    #pragma unroll
    for (int r = 0; r < 18; ++r)
        hreg[r] = sH[r * 64 + lane];

    // ---- Phase B: one thread per output column j, 9 row-accumulators ----
    if (t < DOUT) {
        const int j = t;
        float acc2[NROWS];
        #pragma unroll
        for (int i = 0; i < NROWS; ++i) acc2[i] = 0.0f;

        // k in [0,64): hreg index 2i; k in [64,128): hreg index 2i+1
        #pragma unroll 16
        for (int l = 0; l < 64; ++l) {
            const float w2v = W2[l * DOUT + j];
            #pragma unroll
            for (int i = 0; i < NROWS; ++i)
                acc2[i] = fmaf(readlane_f(hreg[2 * i], l), w2v, acc2[i]);
        }
        #pragma unroll 16
        for (int l = 0; l < 64; ++l) {
            const float w2v = W2[(64 + l) * DOUT + j];
            #pragma unroll
            for (int i = 0; i < NROWS; ++i)
                acc2[i] = fmaf(readlane_f(hreg[2 * i + 1], l), w2v, acc2[i]);
        }

        // epilogue: out[i][j] = (acc2 + b2) * ((input2[i]*Wr[j] + br[j]) * f_c)
        const float f_c = 0.5f * cosf(3.14159265358979323846f * 1.5f / 5.0f) + 1.0f;
        const float b2j = b2[j], Wrj = Wr[j], brj = br[j];
        float pc1 = 0.0f, ptot = 0.0f;
        #pragma unroll
        for (int i = 0; i < NROWS; ++i) {
            const float w = (input2[i] * Wrj + brj) * f_c;
            const float o = (acc2[i] + b2j) * w;
            if (i >= 3 && i < 6)      pc1  += o;
            else if (i < 3)           ptot += o * v_j[i * DOUT + j];
            else                      ptot += o * v_norm[(i - 6) * DOUT + j];
        }
        // wave64 tree reduce
        for (int off = 32; off > 0; off >>= 1) {
            pc1  += __shfl_down(pc1,  off);
            ptot += __shfl_down(ptot, off);
        }
        if (lane == 0) { red[0][wave] = pc1; red[1][wave] = ptot; }
    }
    __syncthreads();

    float sumc1 = 0.0f, total = 0.0f;
    #pragma unroll
    for (int w = 0; w < 6; ++w) { sumc1 += red[0][w]; total += red[1][w]; }

    for (int x = t; x < 3 * DOUT; x += NTHR)
        out[x] = total + v_j[x];
    if (t == 0)
        out[3 * DOUT] = sumc1 + s_j[0];
}

extern "C" void kernel_launch(void* const* d_in, const int* in_sizes, int n_in,
                              void* d_out, int out_size, void* d_ws, size_t ws_size,
                              hipStream_t stream) {
    const float* input1 = (const float*)d_in[0];
    const float* input2 = (const float*)d_in[1];
    const float* v_j    = (const float*)d_in[2];
    const float* s_j    = (const float*)d_in[3];
    const float* v_norm = (const float*)d_in[4];
    const float* W1     = (const float*)d_in[5];
    const float* b1     = (const float*)d_in[6];
    const float* W2     = (const float*)d_in[7];
    const float* b2     = (const float*)d_in[8];
    const float* Wr     = (const float*)d_in[9];
    const float* br     = (const float*)d_in[10];
    float* out = (float*)d_out;

    msg_kernel<<<1, NTHR, 0, stream>>>(input1, input2, v_j, s_j, v_norm,
                                       W1, b1, W2, b2, Wr, br, out);
}

// Round 3
// 11.580 us; speedup vs baseline: 2.9324x; 1.9610x over previous
//
#include <hip/hip_runtime.h>
#include <math.h>

#define NROWS 9
#define DIN   128
#define DH    128
#define DOUT  384
#define NB    12            // 6 j-chunks x 2 k-halves
#define NT1   256

__global__ __launch_bounds__(NT1) void msg_k1(
    const float* __restrict__ input1, const float* __restrict__ input2,
    const float* __restrict__ v_j,    const float* __restrict__ v_norm,
    const float* __restrict__ W1,     const float* __restrict__ b1,
    const float* __restrict__ W2,     const float* __restrict__ b2,
    const float* __restrict__ Wr,     const float* __restrict__ br,
    float f_c, float* __restrict__ wsp)
{
    __shared__ float sA[NROWS * DIN];       // input1 rows 0..8       (4.5 KB)
    __shared__ float sPA[4][NROWS][64];     // layer-1 d-partials     (9 KB)
    __shared__ float sH[NROWS][64];         // silu(h), this k-half   (2.25 KB)
    __shared__ float sPB[4][NROWS][64];     // layer-2 k-partials     (9 KB)

    const int bid    = blockIdx.x;
    const int jchunk = bid >> 1;            // 0..5
    const int khalf  = bid & 1;             // 0..1
    const int j0     = jchunk * 64;
    const int k0     = khalf * 64;
    const int t      = threadIdx.x;
    const int lane   = t & 63;
    const int wave   = t >> 6;              // 0..3

    // stage input1 rows 0..8 (need full d-range for h)
    for (int x = t; x < NROWS * DIN; x += NT1)
        sA[x] = input1[x];
    __syncthreads();

    // ---- Phase A: partial h for k in [k0, k0+64), d split across 4 waves ----
    {
        float acc[NROWS];
        #pragma unroll
        for (int i = 0; i < NROWS; ++i) acc[i] = 0.0f;
        const int dbase = wave * 32;
        #pragma unroll
        for (int dd = 0; dd < 32; ++dd) {
            const int d = dbase + dd;
            const float w1v = W1[d * DH + k0 + lane];      // 64 consecutive floats
            #pragma unroll
            for (int i = 0; i < NROWS; ++i)
                acc[i] = fmaf(sA[i * DIN + d], w1v, acc[i]); // LDS broadcast
        }
        #pragma unroll
        for (int i = 0; i < NROWS; ++i)
            sPA[wave][i][lane] = acc[i];
    }
    __syncthreads();

    // combine d-partials + bias + silu
    for (int x = t; x < NROWS * 64; x += NT1) {
        const int i = x >> 6, kl = x & 63;
        float h = sPA[0][i][kl] + sPA[1][i][kl] + sPA[2][i][kl] + sPA[3][i][kl]
                + b1[k0 + kl];
        sH[i][kl] = h / (1.0f + __expf(-h));
    }
    __syncthreads();

    // ---- Phase B: partial layer-2 for 64 columns, k split across 4 waves ----
    {
        float acc[NROWS];
        #pragma unroll
        for (int i = 0; i < NROWS; ++i) acc[i] = 0.0f;
        const int kbase = wave * 16;
        #pragma unroll
        for (int kk = 0; kk < 16; ++kk) {
            const int kl = kbase + kk;
            const float w2v = W2[(k0 + kl) * DOUT + j0 + lane]; // coalesced
            #pragma unroll
            for (int i = 0; i < NROWS; ++i)
                acc[i] = fmaf(sH[i][kl], w2v, acc[i]);          // LDS broadcast
        }
        #pragma unroll
        for (int i = 0; i < NROWS; ++i)
            sPB[wave][i][lane] = acc[i];
    }
    __syncthreads();

    // ---- epilogue: wave 0, one column per lane ----
    if (wave == 0) {
        const int j = j0 + lane;
        const float Wrj = Wr[j], brj = br[j];
        float pc1 = 0.0f, ptot = 0.0f;
        #pragma unroll
        for (int i = 0; i < NROWS; ++i) {
            float a = sPB[0][i][lane] + sPB[1][i][lane]
                    + sPB[2][i][lane] + sPB[3][i][lane];
            if (khalf == 0) a += b2[j];       // bias added by exactly one k-half
            const float w = (input2[i] * Wrj + brj) * f_c;
            const float o = a * w;
            if (i >= 3 && i < 6)      pc1  += o;
            else if (i < 3)           ptot += o * v_j[i * DOUT + j];
            else                      ptot += o * v_norm[(i - 6) * DOUT + j];
        }
        #pragma unroll
        for (int off = 32; off > 0; off >>= 1) {
            pc1  += __shfl_down(pc1,  off);
            ptot += __shfl_down(ptot, off);
        }
        if (lane == 0) { wsp[bid] = pc1; wsp[NB + bid] = ptot; }
    }
}

__global__ __launch_bounds__(512) void msg_k2(
    const float* __restrict__ v_j, const float* __restrict__ s_j,
    const float* __restrict__ wsp, float* __restrict__ out)
{
    float sumc1 = 0.0f, total = 0.0f;
    #pragma unroll
    for (int b = 0; b < NB; ++b) { sumc1 += wsp[b]; total += wsp[NB + b]; }
    const int t = threadIdx.x;
    for (int x = t; x < 3 * DOUT; x += 512)
        out[x] = total + v_j[x];
    if (t == 0)
        out[3 * DOUT] = sumc1 + s_j[0];
}

extern "C" void kernel_launch(void* const* d_in, const int* in_sizes, int n_in,
                              void* d_out, int out_size, void* d_ws, size_t ws_size,
                              hipStream_t stream) {
    const float* input1 = (const float*)d_in[0];
    const float* input2 = (const float*)d_in[1];
    const float* v_j    = (const float*)d_in[2];
    const float* s_j    = (const float*)d_in[3];
    const float* v_norm = (const float*)d_in[4];
    const float* W1     = (const float*)d_in[5];
    const float* b1     = (const float*)d_in[6];
    const float* W2     = (const float*)d_in[7];
    const float* b2     = (const float*)d_in[8];
    const float* Wr     = (const float*)d_in[9];
    const float* br     = (const float*)d_in[10];
    float* out = (float*)d_out;
    float* wsp = (float*)d_ws;

    const float f_c = 0.5f * cosf(3.14159265358979323846f * 1.5f / 5.0f) + 1.0f;

    msg_k1<<<NB, NT1, 0, stream>>>(input1, input2, v_j, v_norm,
                                   W1, b1, W2, b2, Wr, br, f_c, wsp);
    msg_k2<<<1, 512, 0, stream>>>(v_j, s_j, wsp, out);
}

// Round 7
// 10.227 us; speedup vs baseline: 3.3203x; 1.1323x over previous
//
#include <hip/hip_runtime.h>
#include <math.h>

#define NROWS 9
#define DIN   128
#define DH    128
#define DOUT  384
#define NJ    6              // j-chunks of 64 columns
#define NK    4              // k-quarters of 32
#define NB    (NJ * NK)      // 24 blocks
#define NT    256
#define SENT  0x7F3A91C5u

__device__ __forceinline__ void st_agent_f(float* p, float v) {
    __hip_atomic_store(p, v, __ATOMIC_RELAXED, __HIP_MEMORY_SCOPE_AGENT);
}
__device__ __forceinline__ float ld_agent_f(const float* p) {
    return __hip_atomic_load(p, __ATOMIC_RELAXED, __HIP_MEMORY_SCOPE_AGENT);
}

// ws layout: [0..NB) uint flags | [NB..2NB) float pc1 | [2NB..3NB) float ptot
__global__ __launch_bounds__(NT) void msg_k(
    const float* __restrict__ input1, const float* __restrict__ input2,
    const float* __restrict__ v_j,    const float* __restrict__ s_j,
    const float* __restrict__ v_norm,
    const float* __restrict__ W1,     const float* __restrict__ b1,
    const float* __restrict__ W2,     const float* __restrict__ b2,
    const float* __restrict__ Wr,     const float* __restrict__ br,
    float f_c, unsigned int* __restrict__ flags,
    float* __restrict__ pc1s, float* __restrict__ ptots,
    float* __restrict__ out)
{
    __shared__ float sA[NROWS * DIN];      // input1 rows 0..8 (4.5 KB)
    __shared__ float sPA[8][NROWS][32];    // layer-1 d-partials (9 KB)
    __shared__ float sH[NROWS][32];        // silu(h), this k-quarter
    __shared__ float sPB[4][NROWS][64];    // layer-2 k-partials (9 KB)
    __shared__ float sTot[2];

    const int bid    = blockIdx.x;
    const int jchunk = bid >> 2;           // 0..5
    const int kq     = bid & 3;            // 0..3
    const int j0     = jchunk * 64;
    const int k0     = kq * 32;
    const int t      = threadIdx.x;
    const int lane   = t & 63;
    const int wave   = t >> 6;

    // ---- issue ALL global loads up front: one latency window ----
    const int klA = t & 31;                // phase-A column 0..31
    const int dch = t >> 5;                // phase-A d-chunk 0..7 (16 d each)
    float w1r[16];
    #pragma unroll
    for (int dd = 0; dd < 16; ++dd)
        w1r[dd] = W1[(dch * 16 + dd) * DH + k0 + klA];

    const int jl  = t & 63;                // phase-B column-in-chunk 0..63
    const int kch = t >> 6;                // phase-B k-chunk 0..3 (8 k each)
    float w2r[8];
    #pragma unroll
    for (int kk = 0; kk < 8; ++kk)
        w2r[kk] = W2[(k0 + kch * 8 + kk) * DOUT + j0 + jl];

    const float b1r = b1[k0 + klA];        // valid for both combine iterations (NT%32==0)

    // epilogue operands for wave-0 lane's column
    const int jep = j0 + lane;
    const float Wrj = Wr[jep], brj = br[jep], b2j = b2[jep];
    float in2r[NROWS];
    #pragma unroll
    for (int i = 0; i < NROWS; ++i) in2r[i] = input2[i];
    float vjr[3], vnr[3];
    #pragma unroll
    for (int c = 0; c < 3; ++c) {
        vjr[c] = v_j[c * DOUT + jep];
        vnr[c] = v_norm[c * DOUT + jep];
    }

    // leader-block prefetch for the final broadcast write
    float voutr[5];
    float sjr = 0.0f;
    if (bid == 0) {
        sjr = s_j[0];
        #pragma unroll
        for (int r = 0; r < 5; ++r) {
            const int x = t + NT * r;
            voutr[r] = (x < 3 * DOUT) ? v_j[x] : 0.0f;
        }
    }

    for (int x = t; x < NROWS * DIN; x += NT)
        sA[x] = input1[x];
    __syncthreads();

    // ---- Phase A: partial h for k in [k0,k0+32), d split into 8 chunks ----
    {
        float acc[NROWS];
        #pragma unroll
        for (int i = 0; i < NROWS; ++i) acc[i] = 0.0f;
        #pragma unroll
        for (int dd = 0; dd < 16; ++dd) {
            const int d = dch * 16 + dd;
            #pragma unroll
            for (int i = 0; i < NROWS; ++i)
                acc[i] = fmaf(sA[i * DIN + d], w1r[dd], acc[i]);
        }
        #pragma unroll
        for (int i = 0; i < NROWS; ++i)
            sPA[dch][i][klA] = acc[i];
    }
    __syncthreads();

    // combine d-partials + bias + silu — 288 tasks, STRIDED (288 > NT!)
    for (int x = t; x < NROWS * 32; x += NT) {
        const int i = x >> 5, kl = x & 31;
        float h = b1r;                     // b1[k0+kl] == b1[k0+(t&31)]
        #pragma unroll
        for (int c = 0; c < 8; ++c) h += sPA[c][i][kl];
        sH[i][kl] = h / (1.0f + __expf(-h));
    }
    __syncthreads();

    // ---- Phase B: partial layer-2, k split across 4 waves ----
    {
        float acc[NROWS];
        #pragma unroll
        for (int i = 0; i < NROWS; ++i) acc[i] = 0.0f;
        #pragma unroll
        for (int kk = 0; kk < 8; ++kk) {
            const int kl = kch * 8 + kk;
            #pragma unroll
            for (int i = 0; i < NROWS; ++i)
                acc[i] = fmaf(sH[i][kl], w2r[kk], acc[i]);
        }
        #pragma unroll
        for (int i = 0; i < NROWS; ++i)
            sPB[kch][i][jl] = acc[i];
    }
    __syncthreads();

    // ---- epilogue: wave 0, one column per lane; publish partial ----
    if (wave == 0) {
        float pc1 = 0.0f, ptot = 0.0f;
        #pragma unroll
        for (int i = 0; i < NROWS; ++i) {
            float a = sPB[0][i][lane] + sPB[1][i][lane]
                    + sPB[2][i][lane] + sPB[3][i][lane];
            if (kq == 0) a += b2j;            // bias added by exactly one k-quarter
            const float w = (in2r[i] * Wrj + brj) * f_c;
            const float o = a * w;
            if (i >= 3 && i < 6)      pc1  += o;
            else if (i < 3)           ptot += o * vjr[i];
            else                      ptot += o * vnr[i - 6];
        }
        #pragma unroll
        for (int off = 32; off > 0; off >>= 1) {
            pc1  += __shfl_down(pc1,  off);
            ptot += __shfl_down(ptot, off);
        }
        if (lane == 0) {
            st_agent_f(&pc1s[bid], pc1);
            st_agent_f(&ptots[bid], ptot);
            __hip_atomic_store(&flags[bid], SENT, __ATOMIC_RELEASE,
                               __HIP_MEMORY_SCOPE_AGENT);
        }
    }

    // ---- leader block: wait for all partials, finalize ----
    if (bid == 0) {
        if (wave == 0) {
            const bool mine = lane < NB;
            while (true) {
                bool ok = !mine ||
                    (__hip_atomic_load(&flags[lane], __ATOMIC_ACQUIRE,
                                       __HIP_MEMORY_SCOPE_AGENT) == SENT);
                if (__all(ok)) break;
                __builtin_amdgcn_s_sleep(2);
            }
            float p1 = mine ? ld_agent_f(&pc1s[lane])  : 0.0f;
            float pt = mine ? ld_agent_f(&ptots[lane]) : 0.0f;
            #pragma unroll
            for (int off = 32; off > 0; off >>= 1) {
                p1 += __shfl_down(p1, off);
                pt += __shfl_down(pt, off);
            }
            if (lane == 0) { sTot[0] = p1; sTot[1] = pt; }
        }
        __syncthreads();
        const float sumc1 = sTot[0], total = sTot[1];
        #pragma unroll
        for (int r = 0; r < 5; ++r) {
            const int x = t + NT * r;
            if (x < 3 * DOUT) out[x] = total + voutr[r];
        }
        if (t == 0)
            out[3 * DOUT] = sumc1 + sjr;
    }
}

extern "C" void kernel_launch(void* const* d_in, const int* in_sizes, int n_in,
                              void* d_out, int out_size, void* d_ws, size_t ws_size,
                              hipStream_t stream) {
    const float* input1 = (const float*)d_in[0];
    const float* input2 = (const float*)d_in[1];
    const float* v_j    = (const float*)d_in[2];
    const float* s_j    = (const float*)d_in[3];
    const float* v_norm = (const float*)d_in[4];
    const float* W1     = (const float*)d_in[5];
    const float* b1     = (const float*)d_in[6];
    const float* W2     = (const float*)d_in[7];
    const float* b2     = (const float*)d_in[8];
    const float* Wr     = (const float*)d_in[9];
    const float* br     = (const float*)d_in[10];
    float* out = (float*)d_out;

    unsigned int* flags = (unsigned int*)d_ws;
    float* pc1s  = (float*)d_ws + NB;
    float* ptots = (float*)d_ws + 2 * NB;

    const float f_c = 0.5f * cosf(3.14159265358979323846f * 1.5f / 5.0f) + 1.0f;

    msg_k<<<NB, NT, 0, stream>>>(input1, input2, v_j, s_j, v_norm,
                                 W1, b1, W2, b2, Wr, br, f_c,
                                 flags, pc1s, ptots, out);
}

// Round 8
// 9.666 us; speedup vs baseline: 3.5132x; 1.0581x over previous
//
#include <hip/hip_runtime.h>
#include <math.h>

#define NROWS 9
#define DIN   128
#define DH    128
#define DOUT  384
#define NJ    6              // j-chunks of 64 columns
#define NK    8              // k-eighths of 16
#define NB    (NJ * NK)      // 48 blocks
#define NT    256
#define SENT  0x7F3A91C5u

__device__ __forceinline__ void st_agent_f(float* p, float v) {
    __hip_atomic_store(p, v, __ATOMIC_RELAXED, __HIP_MEMORY_SCOPE_AGENT);
}
__device__ __forceinline__ float ld_agent_f(const float* p) {
    return __hip_atomic_load(p, __ATOMIC_RELAXED, __HIP_MEMORY_SCOPE_AGENT);
}

// ws layout: [0..NB) uint flags | [NB..2NB) float pc1 | [2NB..3NB) float ptot
__global__ __launch_bounds__(NT) void msg_k(
    const float* __restrict__ input1, const float* __restrict__ input2,
    const float* __restrict__ v_j,    const float* __restrict__ s_j,
    const float* __restrict__ v_norm,
    const float* __restrict__ W1,     const float* __restrict__ b1,
    const float* __restrict__ W2,     const float* __restrict__ b2,
    const float* __restrict__ Wr,     const float* __restrict__ br,
    float f_c, unsigned int* __restrict__ flags,
    float* __restrict__ pc1s, float* __restrict__ ptots,
    float* __restrict__ out)
{
    __shared__ float sA[NROWS * DIN];      // input1 rows 0..8 (4.5 KB)
    __shared__ float sPA[16][NROWS][16];   // layer-1 d-partials (9 KB)
    __shared__ float sH[NROWS][16];        // silu(h), this k-sixteenth
    __shared__ float sPB[4][NROWS][64];    // layer-2 k-partials (9 KB)
    __shared__ float sTot[2];

    const int bid    = blockIdx.x;
    const int jchunk = bid >> 3;           // 0..5
    const int kq     = bid & 7;            // 0..7
    const int j0     = jchunk * 64;
    const int k0     = kq * 16;
    const int t      = threadIdx.x;
    const int lane   = t & 63;
    const int wave   = t >> 6;

    // ---- issue ALL global loads up front: one latency window ----
    const int klA = t & 15;                // phase-A column 0..15
    const int dch = t >> 4;                // phase-A d-chunk 0..15 (8 d each)
    float w1r[8];
    #pragma unroll
    for (int dd = 0; dd < 8; ++dd)
        w1r[dd] = W1[(dch * 8 + dd) * DH + k0 + klA];

    const int jl  = t & 63;                // phase-B column-in-chunk 0..63
    const int kch = t >> 6;                // phase-B k-chunk 0..3 (4 k each)
    float w2r[4];
    #pragma unroll
    for (int kk = 0; kk < 4; ++kk)
        w2r[kk] = W2[(k0 + kch * 4 + kk) * DOUT + j0 + jl];

    const float b1r = b1[k0 + klA];        // combine-phase bias (kl == t&15)

    // epilogue operands for wave-0 lane's column
    const int jep = j0 + lane;
    const float Wrj = Wr[jep], brj = br[jep], b2j = b2[jep];
    float in2r[NROWS];
    #pragma unroll
    for (int i = 0; i < NROWS; ++i) in2r[i] = input2[i];
    float vjr[3], vnr[3];
    #pragma unroll
    for (int c = 0; c < 3; ++c) {
        vjr[c] = v_j[c * DOUT + jep];
        vnr[c] = v_norm[c * DOUT + jep];
    }

    // leader-block prefetch for the final broadcast write
    float voutr[5];
    float sjr = 0.0f;
    if (bid == 0) {
        sjr = s_j[0];
        #pragma unroll
        for (int r = 0; r < 5; ++r) {
            const int x = t + NT * r;
            voutr[r] = (x < 3 * DOUT) ? v_j[x] : 0.0f;
        }
    }

    for (int x = t; x < NROWS * DIN; x += NT)
        sA[x] = input1[x];
    __syncthreads();

    // ---- Phase A: partial h for k in [k0,k0+16), d split into 16 chunks ----
    {
        float acc[NROWS];
        #pragma unroll
        for (int i = 0; i < NROWS; ++i) acc[i] = 0.0f;
        #pragma unroll
        for (int dd = 0; dd < 8; ++dd) {
            const int d = dch * 8 + dd;
            #pragma unroll
            for (int i = 0; i < NROWS; ++i)
                acc[i] = fmaf(sA[i * DIN + d], w1r[dd], acc[i]);
        }
        #pragma unroll
        for (int i = 0; i < NROWS; ++i)
            sPA[dch][i][klA] = acc[i];
    }
    __syncthreads();

    // combine d-partials + bias + silu — 144 tasks (< NT, guarded if is safe)
    if (t < NROWS * 16) {
        const int i = t >> 4, kl = t & 15;
        float h = b1r;                     // b1[k0+kl] == b1[k0+(t&15)]
        #pragma unroll
        for (int c = 0; c < 16; ++c) h += sPA[c][i][kl];
        sH[i][kl] = h / (1.0f + __expf(-h));
    }
    __syncthreads();

    // ---- Phase B: partial layer-2, k split across 4 waves ----
    {
        float acc[NROWS];
        #pragma unroll
        for (int i = 0; i < NROWS; ++i) acc[i] = 0.0f;
        #pragma unroll
        for (int kk = 0; kk < 4; ++kk) {
            const int kl = kch * 4 + kk;
            #pragma unroll
            for (int i = 0; i < NROWS; ++i)
                acc[i] = fmaf(sH[i][kl], w2r[kk], acc[i]);
        }
        #pragma unroll
        for (int i = 0; i < NROWS; ++i)
            sPB[kch][i][jl] = acc[i];
    }
    __syncthreads();

    // ---- epilogue: wave 0, one column per lane; publish partial ----
    if (wave == 0) {
        float pc1 = 0.0f, ptot = 0.0f;
        #pragma unroll
        for (int i = 0; i < NROWS; ++i) {
            float a = sPB[0][i][lane] + sPB[1][i][lane]
                    + sPB[2][i][lane] + sPB[3][i][lane];
            if (kq == 0) a += b2j;            // bias added by exactly one k-slice
            const float w = (in2r[i] * Wrj + brj) * f_c;
            const float o = a * w;
            if (i >= 3 && i < 6)      pc1  += o;
            else if (i < 3)           ptot += o * vjr[i];
            else                      ptot += o * vnr[i - 6];
        }
        #pragma unroll
        for (int off = 32; off > 0; off >>= 1) {
            pc1  += __shfl_down(pc1,  off);
            ptot += __shfl_down(ptot, off);
        }
        if (lane == 0) {
            st_agent_f(&pc1s[bid], pc1);
            st_agent_f(&ptots[bid], ptot);
            __hip_atomic_store(&flags[bid], SENT, __ATOMIC_RELEASE,
                               __HIP_MEMORY_SCOPE_AGENT);
        }
    }

    // ---- leader block: wait for all partials, finalize ----
    if (bid == 0) {
        if (wave == 0) {
            const bool mine = lane < NB;
            while (true) {
                bool ok = !mine ||
                    (__hip_atomic_load(&flags[lane], __ATOMIC_ACQUIRE,
                                       __HIP_MEMORY_SCOPE_AGENT) == SENT);
                if (__all(ok)) break;
                __builtin_amdgcn_s_sleep(2);
            }
            float p1 = mine ? ld_agent_f(&pc1s[lane])  : 0.0f;
            float pt = mine ? ld_agent_f(&ptots[lane]) : 0.0f;
            #pragma unroll
            for (int off = 32; off > 0; off >>= 1) {
                p1 += __shfl_down(p1, off);
                pt += __shfl_down(pt, off);
            }
            if (lane == 0) { sTot[0] = p1; sTot[1] = pt; }
        }
        __syncthreads();
        const float sumc1 = sTot[0], total = sTot[1];
        #pragma unroll
        for (int r = 0; r < 5; ++r) {
            const int x = t + NT * r;
            if (x < 3 * DOUT) out[x] = total + voutr[r];
        }
        if (t == 0)
            out[3 * DOUT] = sumc1 + sjr;
    }
}

extern "C" void kernel_launch(void* const* d_in, const int* in_sizes, int n_in,
                              void* d_out, int out_size, void* d_ws, size_t ws_size,
                              hipStream_t stream) {
    const float* input1 = (const float*)d_in[0];
    const float* input2 = (const float*)d_in[1];
    const float* v_j    = (const float*)d_in[2];
    const float* s_j    = (const float*)d_in[3];
    const float* v_norm = (const float*)d_in[4];
    const float* W1     = (const float*)d_in[5];
    const float* b1     = (const float*)d_in[6];
    const float* W2     = (const float*)d_in[7];
    const float* b2     = (const float*)d_in[8];
    const float* Wr     = (const float*)d_in[9];
    const float* br     = (const float*)d_in[10];
    float* out = (float*)d_out;

    unsigned int* flags = (unsigned int*)d_ws;
    float* pc1s  = (float*)d_ws + NB;
    float* ptots = (float*)d_ws + 2 * NB;

    const float f_c = 0.5f * cosf(3.14159265358979323846f * 1.5f / 5.0f) + 1.0f;

    msg_k<<<NB, NT, 0, stream>>>(input1, input2, v_j, s_j, v_norm,
                                 W1, b1, W2, b2, Wr, br, f_c,
                                 flags, pc1s, ptots, out);
}

// Round 9
// 9.417 us; speedup vs baseline: 3.6061x; 1.0264x over previous
//
#include <hip/hip_runtime.h>
#include <math.h>

#define NROWS 9
#define DIN   128
#define DH    128
#define DOUT  384
#define NJ    6              // j-chunks of 64 columns
#define NK    16             // k-slices of 8
#define NB    (NJ * NK)      // 96 worker blocks (+1 leader)
#define NT    256
#define SENT  0x7F3A91C5u

__device__ __forceinline__ void st_agent_f(float* p, float v) {
    __hip_atomic_store(p, v, __ATOMIC_RELAXED, __HIP_MEMORY_SCOPE_AGENT);
}
__device__ __forceinline__ float ld_agent_f(const float* p) {
    return __hip_atomic_load(p, __ATOMIC_RELAXED, __HIP_MEMORY_SCOPE_AGENT);
}

// ws layout: [0..NB) uint flags | [NB..2NB) float pc1 | [2NB..3NB) float ptot
__global__ __launch_bounds__(NT) void msg_k(
    const float* __restrict__ input1, const float* __restrict__ input2,
    const float* __restrict__ v_j,    const float* __restrict__ s_j,
    const float* __restrict__ v_norm,
    const float* __restrict__ W1,     const float* __restrict__ b1,
    const float* __restrict__ W2,     const float* __restrict__ b2,
    const float* __restrict__ Wr,     const float* __restrict__ br,
    float f_c, unsigned int* __restrict__ flags,
    float* __restrict__ pc1s, float* __restrict__ ptots,
    float* __restrict__ out)
{
    const int bid  = blockIdx.x;
    const int t    = threadIdx.x;
    const int lane = t & 63;
    const int wave = t >> 6;

    if (bid < NB) {
        // =================== WORKER ===================
        __shared__ float sA[NROWS * DIN];      // input1 rows 0..8 (4.5 KB)
        __shared__ float sPA[32][NROWS][8];    // layer-1 d-partials (9 KB)
        __shared__ float sH[NROWS][8];         // silu(h), this k-slice
        __shared__ float sPB[4][NROWS][64];    // layer-2 k-partials (9 KB)

        const int jchunk = bid >> 4;           // 0..5
        const int kq     = bid & 15;           // 0..15
        const int j0     = jchunk * 64;
        const int k0     = kq * 8;

        // ---- issue ALL global loads up front: one latency window ----
        const int klA = t & 7;                 // phase-A column 0..7
        const int dch = t >> 3;                // phase-A d-chunk 0..31 (4 d each)
        float w1r[4];
        #pragma unroll
        for (int dd = 0; dd < 4; ++dd)
            w1r[dd] = W1[(dch * 4 + dd) * DH + k0 + klA];

        const int jl  = t & 63;                // phase-B column-in-chunk 0..63
        const int kch = t >> 6;                // phase-B k-chunk 0..3 (2 k each)
        float w2r[2];
        #pragma unroll
        for (int kk = 0; kk < 2; ++kk)
            w2r[kk] = W2[(k0 + kch * 2 + kk) * DOUT + j0 + jl];

        const float b1r = b1[k0 + klA];        // combine bias (task kl == t&7)

        // epilogue operands for wave-0 lane's column
        const int jep = j0 + lane;
        const float Wrj = Wr[jep], brj = br[jep], b2j = b2[jep];
        float in2r[NROWS];
        #pragma unroll
        for (int i = 0; i < NROWS; ++i) in2r[i] = input2[i];
        float vjr[3], vnr[3];
        #pragma unroll
        for (int c = 0; c < 3; ++c) {
            vjr[c] = v_j[c * DOUT + jep];
            vnr[c] = v_norm[c * DOUT + jep];
        }

        // input1 staging, vectorized: 288 float4
        const float4* in4 = (const float4*)input1;
        float4* sA4 = (float4*)sA;
        for (int x = t; x < (NROWS * DIN) / 4; x += NT)
            sA4[x] = in4[x];
        __syncthreads();

        // ---- Phase A: partial h for k in [k0,k0+8), d in 32 chunks of 4 ----
        {
            float acc[NROWS];
            #pragma unroll
            for (int i = 0; i < NROWS; ++i) acc[i] = 0.0f;
            #pragma unroll
            for (int dd = 0; dd < 4; ++dd) {
                const int d = dch * 4 + dd;
                #pragma unroll
                for (int i = 0; i < NROWS; ++i)
                    acc[i] = fmaf(sA[i * DIN + d], w1r[dd], acc[i]);
            }
            #pragma unroll
            for (int i = 0; i < NROWS; ++i)
                sPA[dch][i][klA] = acc[i];
        }
        __syncthreads();

        // combine d-partials + bias + silu — 72 tasks (< NT, guarded if OK)
        if (t < NROWS * 8) {
            const int i = t >> 3, kl = t & 7;
            float h = b1r;                     // b1[k0+kl] == b1[k0+(t&7)]
            #pragma unroll
            for (int c = 0; c < 32; ++c) h += sPA[c][i][kl];
            sH[i][kl] = h / (1.0f + __expf(-h));
        }
        __syncthreads();

        // ---- Phase B: partial layer-2, k split across 4 waves (2 each) ----
        {
            float acc[NROWS];
            #pragma unroll
            for (int i = 0; i < NROWS; ++i) acc[i] = 0.0f;
            #pragma unroll
            for (int kk = 0; kk < 2; ++kk) {
                const int kl = kch * 2 + kk;
                #pragma unroll
                for (int i = 0; i < NROWS; ++i)
                    acc[i] = fmaf(sH[i][kl], w2r[kk], acc[i]);
            }
            #pragma unroll
            for (int i = 0; i < NROWS; ++i)
                sPB[kch][i][jl] = acc[i];
        }
        __syncthreads();

        // ---- epilogue: wave 0, one column per lane; publish partial ----
        if (wave == 0) {
            float pc1 = 0.0f, ptot = 0.0f;
            #pragma unroll
            for (int i = 0; i < NROWS; ++i) {
                float a = sPB[0][i][lane] + sPB[1][i][lane]
                        + sPB[2][i][lane] + sPB[3][i][lane];
                if (kq == 0) a += b2j;        // bias added by exactly one k-slice
                const float w = (in2r[i] * Wrj + brj) * f_c;
                const float o = a * w;
                if (i >= 3 && i < 6)      pc1  += o;
                else if (i < 3)           ptot += o * vjr[i];
                else                      ptot += o * vnr[i - 6];
            }
            #pragma unroll
            for (int off = 32; off > 0; off >>= 1) {
                pc1  += __shfl_down(pc1,  off);
                ptot += __shfl_down(ptot, off);
            }
            if (lane == 0) {
                st_agent_f(&pc1s[bid], pc1);
                st_agent_f(&ptots[bid], ptot);
                __hip_atomic_store(&flags[bid], SENT, __ATOMIC_RELEASE,
                                   __HIP_MEMORY_SCOPE_AGENT);
            }
        }
    } else {
        // =================== LEADER (no slice work) ===================
        __shared__ float sTot[2];

        // prefetch final-write operands
        const float4* vj4 = (const float4*)v_j;
        float4 voutr[2];
        #pragma unroll
        for (int r = 0; r < 2; ++r) {
            const int x = t + NT * r;
            if (x < (3 * DOUT) / 4) voutr[r] = vj4[x];
        }
        const float sjr = s_j[0];

        if (wave == 0) {
            // poll 96 flags: lane covers flags[lane] and (lane<32) flags[64+lane]
            while (true) {
                bool ok0 = __hip_atomic_load(&flags[lane], __ATOMIC_ACQUIRE,
                                             __HIP_MEMORY_SCOPE_AGENT) == SENT;
                bool ok1 = (lane >= 32) ||
                    (__hip_atomic_load(&flags[64 + lane], __ATOMIC_ACQUIRE,
                                       __HIP_MEMORY_SCOPE_AGENT) == SENT);
                if (__all(ok0 && ok1)) break;
                __builtin_amdgcn_s_sleep(2);
            }
            float p1 = ld_agent_f(&pc1s[lane]);
            float pt = ld_agent_f(&ptots[lane]);
            if (lane < 32) {
                p1 += ld_agent_f(&pc1s[64 + lane]);
                pt += ld_agent_f(&ptots[64 + lane]);
            }
            #pragma unroll
            for (int off = 32; off > 0; off >>= 1) {
                p1 += __shfl_down(p1, off);
                pt += __shfl_down(pt, off);
            }
            if (lane == 0) { sTot[0] = p1; sTot[1] = pt; }
        }
        __syncthreads();
        const float total = sTot[1];
        float4* out4 = (float4*)out;
        #pragma unroll
        for (int r = 0; r < 2; ++r) {
            const int x = t + NT * r;
            if (x < (3 * DOUT) / 4) {
                float4 v = voutr[r];
                v.x += total; v.y += total; v.z += total; v.w += total;
                out4[x] = v;
            }
        }
        if (t == 0)
            out[3 * DOUT] = sTot[0] + sjr;
    }
}

extern "C" void kernel_launch(void* const* d_in, const int* in_sizes, int n_in,
                              void* d_out, int out_size, void* d_ws, size_t ws_size,
                              hipStream_t stream) {
    const float* input1 = (const float*)d_in[0];
    const float* input2 = (const float*)d_in[1];
    const float* v_j    = (const float*)d_in[2];
    const float* s_j    = (const float*)d_in[3];
    const float* v_norm = (const float*)d_in[4];
    const float* W1     = (const float*)d_in[5];
    const float* b1     = (const float*)d_in[6];
    const float* W2     = (const float*)d_in[7];
    const float* b2     = (const float*)d_in[8];
    const float* Wr     = (const float*)d_in[9];
    const float* br     = (const float*)d_in[10];
    float* out = (float*)d_out;

    unsigned int* flags = (unsigned int*)d_ws;
    float* pc1s  = (float*)d_ws + NB;
    float* ptots = (float*)d_ws + 2 * NB;

    const float f_c = 0.5f * cosf(3.14159265358979323846f * 1.5f / 5.0f) + 1.0f;

    msg_k<<<NB + 1, NT, 0, stream>>>(input1, input2, v_j, s_j, v_norm,
                                     W1, b1, W2, b2, Wr, br, f_c,
                                     flags, pc1s, ptots, out);
}